// Round 9
// baseline (201.896 us; speedup 1.0000x reference)
//
#include <hip/hip_runtime.h>
#include <stdint.h>

typedef __attribute__((ext_vector_type(4))) int i32x4;

#define M_DIM 8192
#define N_DIM 8192
#define K_DIM 2048
#define BK 128           // i8 elements per K-tile
#define NT (K_DIM / BK)  // 16 K-tiles
#define K64 (K_DIM / 64) // 32 fragment-columns in A'

// ---- pre-pass: x -> i8 in MFMA-fragment-major layout A'; W -> ternary i8 row-major ----
// A' layout: 1 KiB chunk per (m16, k64) fragment, lane-ordered:
//   byte offset = ((m16*K64 + k64)*64 + (k8*16 + fr)) * 16 + (0..15 along k)
__global__ __launch_bounds__(256)
void tl_quant(const float* __restrict__ x, const float* __restrict__ W,
              signed char* __restrict__ xq, signed char* __restrict__ wq,
              float* __restrict__ srow) {
  __shared__ float smax[4];
  const int row = blockIdx.x;
  const int t = threadIdx.x;

  const float* xr = x + (size_t)row * K_DIM;
  float4 v0 = reinterpret_cast<const float4*>(xr)[t * 2];
  float4 v1 = reinterpret_cast<const float4*>(xr)[t * 2 + 1];
  float m = fmaxf(fmaxf(fmaxf(fabsf(v0.x), fabsf(v0.y)), fmaxf(fabsf(v0.z), fabsf(v0.w))),
                  fmaxf(fmaxf(fabsf(v1.x), fabsf(v1.y)), fmaxf(fabsf(v1.z), fabsf(v1.w))));
  #pragma unroll
  for (int off = 1; off < 64; off <<= 1)
    m = fmaxf(m, __shfl_xor(m, off, 64));
  if ((t & 63) == 0) smax[t >> 6] = m;
  __syncthreads();
  m = fmaxf(fmaxf(smax[0], smax[1]), fmaxf(smax[2], smax[3]));
  const float rs = (m > 0.f) ? 127.0f / m : 0.f;

  union { signed char c[8]; uint2 u; } qx;
  qx.c[0] = (signed char)__float2int_rn(v0.x * rs);
  qx.c[1] = (signed char)__float2int_rn(v0.y * rs);
  qx.c[2] = (signed char)__float2int_rn(v0.z * rs);
  qx.c[3] = (signed char)__float2int_rn(v0.w * rs);
  qx.c[4] = (signed char)__float2int_rn(v1.x * rs);
  qx.c[5] = (signed char)__float2int_rn(v1.y * rs);
  qx.c[6] = (signed char)__float2int_rn(v1.z * rs);
  qx.c[7] = (signed char)__float2int_rn(v1.w * rs);
  {
    const int m16 = row >> 4, fr = row & 15;
    const int k64 = t >> 3, k8 = (t >> 1) & 3, b8 = t & 1;
    const size_t u2 = (((size_t)m16 * K64 + k64) * 64 + (k8 * 16 + fr)) * 2 + b8;
    reinterpret_cast<uint2*>(xq)[u2] = qx.u;
  }

  const float* wr = W + (size_t)row * K_DIM;
  float4 w0 = reinterpret_cast<const float4*>(wr)[t * 2];
  float4 w1 = reinterpret_cast<const float4*>(wr)[t * 2 + 1];
  union { signed char c[8]; uint2 u; } qw;
  qw.c[0] = (fabsf(w0.x) > 0.4f) ? ((w0.x > 0.f) ? 1 : -1) : 0;
  qw.c[1] = (fabsf(w0.y) > 0.4f) ? ((w0.y > 0.f) ? 1 : -1) : 0;
  qw.c[2] = (fabsf(w0.z) > 0.4f) ? ((w0.z > 0.f) ? 1 : -1) : 0;
  qw.c[3] = (fabsf(w0.w) > 0.4f) ? ((w0.w > 0.f) ? 1 : -1) : 0;
  qw.c[4] = (fabsf(w1.x) > 0.4f) ? ((w1.x > 0.f) ? 1 : -1) : 0;
  qw.c[5] = (fabsf(w1.y) > 0.4f) ? ((w1.y > 0.f) ? 1 : -1) : 0;
  qw.c[6] = (fabsf(w1.z) > 0.4f) ? ((w1.z > 0.f) ? 1 : -1) : 0;
  qw.c[7] = (fabsf(w1.w) > 0.4f) ? ((w1.w > 0.f) ? 1 : -1) : 0;
  reinterpret_cast<uint2*>(wq + (size_t)row * K_DIM)[t] = qw.u;

  if (t == 0) srow[row] = (m > 0.f) ? m / 127.0f : 0.f;
}

// ---- i8 GEMM: C[t,o] = srow[t] * sum_k xq[t,k]*wq[o,k] ----
// vs R8: B double-buffered (2x16 KiB LDS); per iteration we issue BOTH the
// B-stage for tile T+1 and the A-fragment loads for tile T+1 (into the spare
// register set), THEN compute tile T from already-resident data, then one
// vmcnt(0)+barrier that drains loads issued a full compute phase earlier
// -> near-zero stall, one barrier/iter. 2x unroll with named avA/avB sets.
__global__ __launch_bounds__(256, 3)
void tl_gemm(const signed char* __restrict__ Af, const signed char* __restrict__ B,
             const float* __restrict__ srow, float* __restrict__ C) {
  __shared__ signed char sB[2][128 * 128];   // 2 x 16 KiB

  const int tid  = threadIdx.x;
  const int lane = tid & 63;
  const int w    = tid >> 6;       // wave 0..3
  const int wr   = w >> 1;         // wave row (0..1)
  const int wc   = w & 1;          // wave col (0..1)

  // XCD-aware supertile raster: nwg = 4096 = 8 XCDs x 8 supertiles x 64 tiles.
  const int bid = blockIdx.x;
  const int xcd = bid & 7;
  const int idx = bid >> 3;
  const int s   = idx >> 6;
  const int t   = idx & 63;
  const int tm  = xcd * 8 + (t & 7);
  const int tn  = s * 8 + (t >> 3);
  const size_t brow = (size_t)tm * 128;
  const size_t bcol = (size_t)tn * 128;

  // B staging: per issue a wave covers 8 rows x 128 B (64 lanes x 16 B)
  const int srow0  = w * 32 + (lane >> 3);
  const int scolb0 = (lane & 7) * 16;

  const int fr = lane & 15;        // fragment row
  const int k8 = lane >> 4;        // k-group 0..3

  // A' addressing
  const int m16g = tm * 8 + wr * 4;
  const size_t laneoff = (size_t)lane * 16;
  const signed char* Afb = Af + ((size_t)m16g * K64 << 10) + laneoff;

#define STAGE_B(bufi, kt) do {                                                        \
    _Pragma("unroll")                                                                 \
    for (int j = 0; j < 4; ++j) {                                                     \
      int row  = srow0 + j * 8;                                                       \
      int colb = scolb0 ^ ((row & 7) << 4);                                           \
      const signed char* gb = B + (bcol + row) * (size_t)K_DIM + (kt) + colb;         \
      signed char* lb = &sB[bufi][(w * 32 + j * 8) * 128];                            \
      __builtin_amdgcn_global_load_lds((const __attribute__((address_space(1))) void*)gb, \
          (__attribute__((address_space(3))) void*)lb, 16, 0, 0);                     \
    }                                                                                 \
  } while (0)

#define AV_LOAD(dst, k64v) do {                                                       \
    _Pragma("unroll")                                                                 \
    for (int mi = 0; mi < 4; ++mi)                                                    \
      dst[mi] = *(const i32x4*)(Afb + (((size_t)mi * K64 + (k64v)) << 10));           \
  } while (0)

#define COMPUTE(c, av0, av1) do {                                                     \
    i32x4 bv[4];                                                                      \
    _Pragma("unroll")                                                                 \
    for (int ni = 0; ni < 4; ++ni) {                                                  \
      int row  = wc * 64 + ni * 16 + fr;                                              \
      int colb = (k8 * 16) ^ ((row & 7) << 4);                                        \
      bv[ni] = *(const i32x4*)&sB[c][row * 128 + colb];                               \
    }                                                                                 \
    _Pragma("unroll")                                                                 \
    for (int mi = 0; mi < 4; ++mi)                                                    \
      _Pragma("unroll")                                                               \
      for (int ni = 0; ni < 4; ++ni)                                                  \
        acc[mi][ni] = __builtin_amdgcn_mfma_i32_16x16x64_i8(av0[mi], bv[ni], acc[mi][ni], 0, 0, 0); \
    _Pragma("unroll")                                                                 \
    for (int ni = 0; ni < 4; ++ni) {                                                  \
      int row  = wc * 64 + ni * 16 + fr;                                              \
      int colb = (64 + k8 * 16) ^ ((row & 7) << 4);                                   \
      bv[ni] = *(const i32x4*)&sB[c][row * 128 + colb];                               \
    }                                                                                 \
    _Pragma("unroll")                                                                 \
    for (int mi = 0; mi < 4; ++mi)                                                    \
      _Pragma("unroll")                                                               \
      for (int ni = 0; ni < 4; ++ni)                                                  \
        acc[mi][ni] = __builtin_amdgcn_mfma_i32_16x16x64_i8(av1[mi], bv[ni], acc[mi][ni], 0, 0, 0); \
  } while (0)

  i32x4 acc[4][4];
  #pragma unroll
  for (int i = 0; i < 4; ++i)
    #pragma unroll
    for (int j = 0; j < 4; ++j)
      acc[i][j] = i32x4{0, 0, 0, 0};

  i32x4 avA0[4], avA1[4], avB0[4], avB1[4];

  // ---- prologue: tile 0 resident ----
  STAGE_B(0, 0);
  AV_LOAD(avA0, 0); AV_LOAD(avA1, 1);
  asm volatile("s_waitcnt vmcnt(0)" ::: "memory");
  __builtin_amdgcn_s_barrier();
  __builtin_amdgcn_sched_barrier(0);

  #pragma unroll 1
  for (int T = 0; T < NT; T += 2) {
    // ---- even iter: compute T (buf0/avA), prefetch T+1 (buf1/avB) ----
    STAGE_B(1, (T + 1) * BK);
    AV_LOAD(avB0, 2 * (T + 1)); AV_LOAD(avB1, 2 * (T + 1) + 1);
    __builtin_amdgcn_sched_barrier(0);          // pin: loads issue before compute
    COMPUTE(0, avA0, avA1);
    asm volatile("s_waitcnt vmcnt(0)" ::: "memory");   // issued a phase ago: ~free
    __builtin_amdgcn_s_barrier();
    __builtin_amdgcn_sched_barrier(0);

    // ---- odd iter: compute T+1 (buf1/avB), prefetch T+2 (buf0/avA) ----
    const int kt2  = ((T + 2) & (NT - 1)) * BK;        // wraps to dummy on last iter
    const int k642 = (2 * (T + 2)) & (2 * NT - 1);
    STAGE_B(0, kt2);
    AV_LOAD(avA0, k642); AV_LOAD(avA1, k642 + 1);
    __builtin_amdgcn_sched_barrier(0);
    COMPUTE(1, avB0, avB1);
    asm volatile("s_waitcnt vmcnt(0)" ::: "memory");
    __builtin_amdgcn_s_barrier();
    __builtin_amdgcn_sched_barrier(0);
  }

  // ---- epilogue: C/D layout col = lane&15, row = (lane>>4)*4 + reg; scale by srow ----
  #pragma unroll
  for (int mi = 0; mi < 4; ++mi) {
    size_t r0 = brow + wr * 64 + mi * 16 + k8 * 4;
    float sc0 = srow[r0 + 0], sc1 = srow[r0 + 1], sc2 = srow[r0 + 2], sc3 = srow[r0 + 3];
    #pragma unroll
    for (int ni = 0; ni < 4; ++ni) {
      i32x4 v = acc[mi][ni];
      size_t c0 = bcol + wc * 64 + ni * 16 + fr;
      C[(r0 + 0) * N_DIM + c0] = sc0 * (float)v[0];
      C[(r0 + 1) * N_DIM + c0] = sc1 * (float)v[1];
      C[(r0 + 2) * N_DIM + c0] = sc2 * (float)v[2];
      C[(r0 + 3) * N_DIM + c0] = sc3 * (float)v[3];
    }
  }
#undef STAGE_B
#undef AV_LOAD
#undef COMPUTE
}

// Fallback (only if ws_size is unexpectedly small): fused ternarize + fp32 tiled GEMM.
__global__ void tl_naive(const float* __restrict__ x, const float* __restrict__ W,
                         float* __restrict__ out) {
  __shared__ float sx[16][17];
  __shared__ float sw[16][17];
  int tx = threadIdx.x, ty = threadIdx.y;
  int row = blockIdx.y * 16 + ty;
  int col = blockIdx.x * 16 + tx;
  float acc = 0.f;
  for (int kt = 0; kt < K_DIM; kt += 16) {
    sx[ty][tx] = x[(size_t)row * K_DIM + kt + tx];
    float wv = W[(size_t)(blockIdx.x * 16 + ty) * K_DIM + kt + tx];
    sw[ty][tx] = (fabsf(wv) > 0.4f) ? ((wv > 0.f) ? 1.f : -1.f) : 0.f;
    __syncthreads();
    #pragma unroll
    for (int k = 0; k < 16; ++k) acc += sx[ty][k] * sw[tx][k];
    __syncthreads();
  }
  out[(size_t)row * N_DIM + col] = acc;
}

extern "C" void kernel_launch(void* const* d_in, const int* in_sizes, int n_in,
                              void* d_out, int out_size, void* d_ws, size_t ws_size,
                              hipStream_t stream) {
  const float* x = (const float*)d_in[0];
  const float* W = (const float*)d_in[1];
  float* out = (float*)d_out;

  const size_t xq_bytes = (size_t)M_DIM * K_DIM;          // 16 MiB
  const size_t wq_bytes = (size_t)N_DIM * K_DIM;          // 16 MiB
  const size_t need = xq_bytes + wq_bytes + M_DIM * sizeof(float);

  if (ws_size >= need) {
    signed char* xq = (signed char*)d_ws;                 // fragment-major A'
    signed char* wq = xq + xq_bytes;                      // row-major ternary W
    float* srow = (float*)(wq + wq_bytes);
    tl_quant<<<M_DIM, 256, 0, stream>>>(x, W, xq, wq, srow);
    tl_gemm<<<4096, 256, 0, stream>>>(xq, wq, srow, out);
  } else {
    dim3 g(N_DIM / 16, M_DIM / 16), b(16, 16);
    tl_naive<<<g, b, 0, stream>>>(x, W, out);
  }
}

// Round 10
// 194.358 us; speedup vs baseline: 1.0388x; 1.0388x over previous
//
#include <hip/hip_runtime.h>
#include <stdint.h>

typedef __attribute__((ext_vector_type(4))) int i32x4;

#define M_DIM 8192
#define N_DIM 8192
#define K_DIM 2048
#define BK 128           // i8 elements per K-tile (128 B per row)
#define NT (K_DIM / BK)  // 16 K-tiles

// ---- pre-pass: per-row i8 quantization of x, exact ternarize of W (row-major) ----
__global__ __launch_bounds__(256)
void tl_quant(const float* __restrict__ x, const float* __restrict__ W,
              signed char* __restrict__ xq, signed char* __restrict__ wq,
              float* __restrict__ srow) {
  __shared__ float smax[4];
  const int row = blockIdx.x;
  const int t = threadIdx.x;

  const float* xr = x + (size_t)row * K_DIM;
  float4 v0 = reinterpret_cast<const float4*>(xr)[t * 2];
  float4 v1 = reinterpret_cast<const float4*>(xr)[t * 2 + 1];
  float m = fmaxf(fmaxf(fmaxf(fabsf(v0.x), fabsf(v0.y)), fmaxf(fabsf(v0.z), fabsf(v0.w))),
                  fmaxf(fmaxf(fabsf(v1.x), fabsf(v1.y)), fmaxf(fabsf(v1.z), fabsf(v1.w))));
  #pragma unroll
  for (int off = 1; off < 64; off <<= 1)
    m = fmaxf(m, __shfl_xor(m, off, 64));
  if ((t & 63) == 0) smax[t >> 6] = m;
  __syncthreads();
  m = fmaxf(fmaxf(smax[0], smax[1]), fmaxf(smax[2], smax[3]));
  const float rs = (m > 0.f) ? 127.0f / m : 0.f;

  union { signed char c[8]; uint2 u; } qx;
  qx.c[0] = (signed char)__float2int_rn(v0.x * rs);
  qx.c[1] = (signed char)__float2int_rn(v0.y * rs);
  qx.c[2] = (signed char)__float2int_rn(v0.z * rs);
  qx.c[3] = (signed char)__float2int_rn(v0.w * rs);
  qx.c[4] = (signed char)__float2int_rn(v1.x * rs);
  qx.c[5] = (signed char)__float2int_rn(v1.y * rs);
  qx.c[6] = (signed char)__float2int_rn(v1.z * rs);
  qx.c[7] = (signed char)__float2int_rn(v1.w * rs);
  reinterpret_cast<uint2*>(xq + (size_t)row * K_DIM)[t] = qx.u;

  const float* wr = W + (size_t)row * K_DIM;
  float4 w0 = reinterpret_cast<const float4*>(wr)[t * 2];
  float4 w1 = reinterpret_cast<const float4*>(wr)[t * 2 + 1];
  union { signed char c[8]; uint2 u; } qw;
  qw.c[0] = (fabsf(w0.x) > 0.4f) ? ((w0.x > 0.f) ? 1 : -1) : 0;
  qw.c[1] = (fabsf(w0.y) > 0.4f) ? ((w0.y > 0.f) ? 1 : -1) : 0;
  qw.c[2] = (fabsf(w0.z) > 0.4f) ? ((w0.z > 0.f) ? 1 : -1) : 0;
  qw.c[3] = (fabsf(w0.w) > 0.4f) ? ((w0.w > 0.f) ? 1 : -1) : 0;
  qw.c[4] = (fabsf(w1.x) > 0.4f) ? ((w1.x > 0.f) ? 1 : -1) : 0;
  qw.c[5] = (fabsf(w1.y) > 0.4f) ? ((w1.y > 0.f) ? 1 : -1) : 0;
  qw.c[6] = (fabsf(w1.z) > 0.4f) ? ((w1.z > 0.f) ? 1 : -1) : 0;
  qw.c[7] = (fabsf(w1.w) > 0.4f) ? ((w1.w > 0.f) ? 1 : -1) : 0;
  reinterpret_cast<uint2*>(wq + (size_t)row * K_DIM)[t] = qw.u;

  if (t == 0) srow[row] = (m > 0.f) ? m / 127.0f : 0.f;
}

// ---- i8 GEMM: C[t,o] = srow[t] * sum_k xq[t,k]*wq[o,k] ----
// R7 structure (single-buffer 2-barrier loop, byte XOR swizzle (row&7)<<4
// both-sides, supertile raster, 4 blocks/CU) with FATTER WAVES:
// 2-wave blocks, each wave computes 128x64 (8x4 frags, 128 AGPR acc).
// Per-block LDS traffic 96->80 KB/K-tile, ds_reads/MFMA 0.5->0.375,
// while keeping 4 independent barrier groups per CU (the R5->R7 TLP win).
__global__ __launch_bounds__(128, 2)
void tl_gemm(const signed char* __restrict__ A, const signed char* __restrict__ B,
             const float* __restrict__ srow, float* __restrict__ C) {
  __shared__ signed char sA[128 * 128];   // 16 KiB
  __shared__ signed char sB[128 * 128];   // 16 KiB

  const int tid  = threadIdx.x;
  const int lane = tid & 63;
  const int w    = tid >> 6;       // wave 0..1 -> col half

  // XCD-aware supertile raster: nwg = 4096 = 8 XCDs x 8 supertiles x 64 tiles.
  const int bid = blockIdx.x;
  const int xcd = bid & 7;
  const int idx = bid >> 3;        // 0..511
  const int s   = idx >> 6;        // supertile 0..7 (tn band)
  const int t   = idx & 63;
  const int tm  = xcd * 8 + (t & 7);
  const int tn  = s * 8 + (t >> 3);
  const size_t brow = (size_t)tm * 128;
  const size_t bcol = (size_t)tn * 128;

  // staging: wave w covers rows [w*64, w*64+64); per issue 8 rows x 128 B
  const int srow0 = w * 64 + (lane >> 3);                    // + j*8
  const int scolb = ((lane & 7) * 16) ^ ((lane >> 3) << 4);  // swizzled source col (j-invariant)
  const signed char* gA0 = A + (brow + srow0) * (size_t)K_DIM + scolb;
  const signed char* gB0 = B + (bcol + srow0) * (size_t)K_DIM + scolb;

  i32x4 acc[8][4];
  #pragma unroll
  for (int i = 0; i < 8; ++i)
    #pragma unroll
    for (int j = 0; j < 4; ++j)
      acc[i][j] = i32x4{0, 0, 0, 0};

  const int fr = lane & 15;        // fragment row
  const int k8 = lane >> 4;        // k-group 0..3

  for (int kt = 0; kt < K_DIM; kt += BK) {
    // ---- stage A,B tiles (linear LDS dest, swizzled global source) ----
    #pragma unroll
    for (int j = 0; j < 8; ++j) {
      const signed char* ga = gA0 + (size_t)j * 8 * K_DIM + kt;
      const signed char* gb = gB0 + (size_t)j * 8 * K_DIM + kt;
      signed char* la = &sA[(w * 64 + j * 8) * 128];   // wave-uniform base
      signed char* lb = &sB[(w * 64 + j * 8) * 128];
      __builtin_amdgcn_global_load_lds((const __attribute__((address_space(1))) void*)ga,
                                       (__attribute__((address_space(3))) void*)la, 16, 0, 0);
      __builtin_amdgcn_global_load_lds((const __attribute__((address_space(1))) void*)gb,
                                       (__attribute__((address_space(3))) void*)lb, 16, 0, 0);
    }
    __syncthreads();   // drains vmcnt before any wave reads LDS

    // ---- compute: 2 k-halves (64 elems each) x 32 MFMA ----
    #pragma unroll
    for (int kk = 0; kk < 2; ++kk) {
      i32x4 av[8], bv[4];
      #pragma unroll
      for (int mi = 0; mi < 8; ++mi) {
        int row  = mi * 16 + fr;
        int colb = (kk * 64 + k8 * 16) ^ ((row & 7) << 4);
        av[mi] = *(const i32x4*)&sA[row * 128 + colb];
      }
      #pragma unroll
      for (int ni = 0; ni < 4; ++ni) {
        int row  = w * 64 + ni * 16 + fr;
        int colb = (kk * 64 + k8 * 16) ^ ((row & 7) << 4);
        bv[ni] = *(const i32x4*)&sB[row * 128 + colb];
      }
      #pragma unroll
      for (int mi = 0; mi < 8; ++mi)
        #pragma unroll
        for (int ni = 0; ni < 4; ++ni)
          acc[mi][ni] = __builtin_amdgcn_mfma_i32_16x16x64_i8(av[mi], bv[ni], acc[mi][ni], 0, 0, 0);
    }
    __syncthreads();
  }

  // ---- epilogue: C/D layout col = lane&15, row = (lane>>4)*4 + reg; scale by srow ----
  #pragma unroll
  for (int mi = 0; mi < 8; ++mi) {
    size_t r0 = brow + mi * 16 + k8 * 4;
    float sc0 = srow[r0 + 0], sc1 = srow[r0 + 1], sc2 = srow[r0 + 2], sc3 = srow[r0 + 3];
    #pragma unroll
    for (int ni = 0; ni < 4; ++ni) {
      i32x4 v = acc[mi][ni];
      size_t c0 = bcol + w * 64 + ni * 16 + fr;
      C[(r0 + 0) * N_DIM + c0] = sc0 * (float)v[0];
      C[(r0 + 1) * N_DIM + c0] = sc1 * (float)v[1];
      C[(r0 + 2) * N_DIM + c0] = sc2 * (float)v[2];
      C[(r0 + 3) * N_DIM + c0] = sc3 * (float)v[3];
    }
  }
}

// Fallback (only if ws_size is unexpectedly small): fused ternarize + fp32 tiled GEMM.
__global__ void tl_naive(const float* __restrict__ x, const float* __restrict__ W,
                         float* __restrict__ out) {
  __shared__ float sx[16][17];
  __shared__ float sw[16][17];
  int tx = threadIdx.x, ty = threadIdx.y;
  int row = blockIdx.y * 16 + ty;
  int col = blockIdx.x * 16 + tx;
  float acc = 0.f;
  for (int kt = 0; kt < K_DIM; kt += 16) {
    sx[ty][tx] = x[(size_t)row * K_DIM + kt + tx];
    float wv = W[(size_t)(blockIdx.x * 16 + ty) * K_DIM + kt + tx];
    sw[ty][tx] = (fabsf(wv) > 0.4f) ? ((wv > 0.f) ? 1.f : -1.f) : 0.f;
    __syncthreads();
    #pragma unroll
    for (int k = 0; k < 16; ++k) acc += sx[ty][k] * sw[tx][k];
    __syncthreads();
  }
  out[(size_t)row * N_DIM + col] = acc;
}

extern "C" void kernel_launch(void* const* d_in, const int* in_sizes, int n_in,
                              void* d_out, int out_size, void* d_ws, size_t ws_size,
                              hipStream_t stream) {
  const float* x = (const float*)d_in[0];
  const float* W = (const float*)d_in[1];
  float* out = (float*)d_out;

  const size_t xq_bytes = (size_t)M_DIM * K_DIM;          // 16 MiB
  const size_t wq_bytes = (size_t)N_DIM * K_DIM;          // 16 MiB
  const size_t need = xq_bytes + wq_bytes + M_DIM * sizeof(float);

  if (ws_size >= need) {
    signed char* xq = (signed char*)d_ws;                 // row-major i8 x
    signed char* wq = xq + xq_bytes;                      // row-major ternary W
    float* srow = (float*)(wq + wq_bytes);
    tl_quant<<<M_DIM, 256, 0, stream>>>(x, W, xq, wq, srow);
    tl_gemm<<<4096, 128, 0, stream>>>(xq, wq, srow, out);
  } else {
    dim3 g(N_DIM / 16, M_DIM / 16), b(16, 16);
    tl_naive<<<g, b, 0, stream>>>(x, W, out);
  }
}

// Round 11
// 191.027 us; speedup vs baseline: 1.0569x; 1.0174x over previous
//
#include <hip/hip_runtime.h>
#include <stdint.h>

typedef __attribute__((ext_vector_type(4))) int i32x4;

#define M_DIM 8192
#define N_DIM 8192
#define K_DIM 2048
#define BK 128           // i8 elements per K-tile (128 B per row)
#define NT (K_DIM / BK)  // 16 K-tiles

// ---- pre-pass A: per-row i8 quantization of x (row-max reduce + scale) ----
__global__ __launch_bounds__(256)
void tl_quant_x(const float* __restrict__ x, signed char* __restrict__ xq,
                float* __restrict__ srow) {
  __shared__ float smax[4];
  const int row = blockIdx.x;
  const int t = threadIdx.x;

  const float* xr = x + (size_t)row * K_DIM;
  float4 v0 = reinterpret_cast<const float4*>(xr)[t * 2];
  float4 v1 = reinterpret_cast<const float4*>(xr)[t * 2 + 1];
  float m = fmaxf(fmaxf(fmaxf(fabsf(v0.x), fabsf(v0.y)), fmaxf(fabsf(v0.z), fabsf(v0.w))),
                  fmaxf(fmaxf(fabsf(v1.x), fabsf(v1.y)), fmaxf(fabsf(v1.z), fabsf(v1.w))));
  #pragma unroll
  for (int off = 1; off < 64; off <<= 1)
    m = fmaxf(m, __shfl_xor(m, off, 64));
  if ((t & 63) == 0) smax[t >> 6] = m;
  __syncthreads();
  m = fmaxf(fmaxf(smax[0], smax[1]), fmaxf(smax[2], smax[3]));
  const float rs = (m > 0.f) ? 127.0f / m : 0.f;

  union { signed char c[8]; uint2 u; } qx;
  qx.c[0] = (signed char)__float2int_rn(v0.x * rs);
  qx.c[1] = (signed char)__float2int_rn(v0.y * rs);
  qx.c[2] = (signed char)__float2int_rn(v0.z * rs);
  qx.c[3] = (signed char)__float2int_rn(v0.w * rs);
  qx.c[4] = (signed char)__float2int_rn(v1.x * rs);
  qx.c[5] = (signed char)__float2int_rn(v1.y * rs);
  qx.c[6] = (signed char)__float2int_rn(v1.z * rs);
  qx.c[7] = (signed char)__float2int_rn(v1.w * rs);
  reinterpret_cast<uint2*>(xq + (size_t)row * K_DIM)[t] = qx.u;

  if (t == 0) srow[row] = (m > 0.f) ? m / 127.0f : 0.f;
}

// ---- pre-pass B: pure streaming ternarize of W (no reduction, no barriers) ----
__global__ __launch_bounds__(256)
void tl_quant_w(const float* __restrict__ W, signed char* __restrict__ wq, int n8) {
  int i = blockIdx.x * blockDim.x + threadIdx.x;
  if (i >= n8) return;
  float4 w0 = reinterpret_cast<const float4*>(W)[i * 2];
  float4 w1 = reinterpret_cast<const float4*>(W)[i * 2 + 1];
  union { signed char c[8]; uint2 u; } qw;
  qw.c[0] = (fabsf(w0.x) > 0.4f) ? ((w0.x > 0.f) ? 1 : -1) : 0;
  qw.c[1] = (fabsf(w0.y) > 0.4f) ? ((w0.y > 0.f) ? 1 : -1) : 0;
  qw.c[2] = (fabsf(w0.z) > 0.4f) ? ((w0.z > 0.f) ? 1 : -1) : 0;
  qw.c[3] = (fabsf(w0.w) > 0.4f) ? ((w0.w > 0.f) ? 1 : -1) : 0;
  qw.c[4] = (fabsf(w1.x) > 0.4f) ? ((w1.x > 0.f) ? 1 : -1) : 0;
  qw.c[5] = (fabsf(w1.y) > 0.4f) ? ((w1.y > 0.f) ? 1 : -1) : 0;
  qw.c[6] = (fabsf(w1.z) > 0.4f) ? ((w1.z > 0.f) ? 1 : -1) : 0;
  qw.c[7] = (fabsf(w1.w) > 0.4f) ? ((w1.w > 0.f) ? 1 : -1) : 0;
  reinterpret_cast<uint2*>(wq)[i] = qw.u;
}

// ---- i8 GEMM: C[t,o] = srow[t] * sum_k xq[t,k]*wq[o,k] ----
// R7 verbatim (proven best): 128x128 tile, 4 waves 2x2 (64x64 each),
// single-buffer 2-barrier loop, byte XOR swizzle (row&7)<<4 both-sides
// (0 conflicts), supertile raster (XCD owns an 8-row tm band; 8x8
// supertiles -> L2-resident panels), __launch_bounds__(256,4): 4 blocks/CU
// (the R5->R7 TLP win that hides the per-tile vmcnt drain).
__global__ __launch_bounds__(256, 4)
void tl_gemm(const signed char* __restrict__ A, const signed char* __restrict__ B,
             const float* __restrict__ srow, float* __restrict__ C) {
  __shared__ signed char sA[128 * 128];   // 16 KiB
  __shared__ signed char sB[128 * 128];   // 16 KiB

  const int tid  = threadIdx.x;
  const int lane = tid & 63;
  const int w    = tid >> 6;       // wave 0..3
  const int wr   = w >> 1;         // wave row (0..1)
  const int wc   = w & 1;          // wave col (0..1)

  // XCD-aware supertile raster: nwg = 4096 = 8 XCDs x 8 supertiles x 64 tiles.
  const int bid = blockIdx.x;
  const int xcd = bid & 7;
  const int idx = bid >> 3;        // 0..511
  const int s   = idx >> 6;        // supertile 0..7 (tn band)
  const int t   = idx & 63;
  const int tm  = xcd * 8 + (t & 7);
  const int tn  = s * 8 + (t >> 3);
  const size_t brow = (size_t)tm * 128;
  const size_t bcol = (size_t)tn * 128;

  // staging: per issue a wave covers 8 rows x 128 B (64 lanes x 16 B)
  const int srow0  = w * 32 + (lane >> 3);
  const int scolb0 = (lane & 7) * 16;          // byte col base

  i32x4 acc[4][4];
  #pragma unroll
  for (int i = 0; i < 4; ++i)
    #pragma unroll
    for (int j = 0; j < 4; ++j)
      acc[i][j] = i32x4{0, 0, 0, 0};

  const int fr = lane & 15;        // fragment row
  const int k8 = lane >> 4;        // k-group 0..3

  for (int kt = 0; kt < K_DIM; kt += BK) {
    // ---- stage A,B tiles (linear LDS dest, swizzled global source) ----
    #pragma unroll
    for (int j = 0; j < 4; ++j) {
      int row  = srow0 + j * 8;
      int colb = scolb0 ^ ((row & 7) << 4);
      const signed char* ga = A + (brow + row) * (size_t)K_DIM + kt + colb;
      const signed char* gb = B + (bcol + row) * (size_t)K_DIM + kt + colb;
      signed char* la = &sA[(w * 32 + j * 8) * 128];   // wave-uniform base
      signed char* lb = &sB[(w * 32 + j * 8) * 128];
      __builtin_amdgcn_global_load_lds((const __attribute__((address_space(1))) void*)ga,
                                       (__attribute__((address_space(3))) void*)la, 16, 0, 0);
      __builtin_amdgcn_global_load_lds((const __attribute__((address_space(1))) void*)gb,
                                       (__attribute__((address_space(3))) void*)lb, 16, 0, 0);
    }
    __syncthreads();   // drains vmcnt before any wave reads LDS

    // ---- compute: 2 k-halves (64 elems each) x 16 MFMA ----
    #pragma unroll
    for (int kk = 0; kk < 2; ++kk) {
      i32x4 av[4], bv[4];
      #pragma unroll
      for (int mi = 0; mi < 4; ++mi) {
        int row  = wr * 64 + mi * 16 + fr;
        int colb = (kk * 64 + k8 * 16) ^ ((row & 7) << 4);
        av[mi] = *(const i32x4*)&sA[row * 128 + colb];
      }
      #pragma unroll
      for (int ni = 0; ni < 4; ++ni) {
        int row  = wc * 64 + ni * 16 + fr;
        int colb = (kk * 64 + k8 * 16) ^ ((row & 7) << 4);
        bv[ni] = *(const i32x4*)&sB[row * 128 + colb];
      }
      #pragma unroll
      for (int mi = 0; mi < 4; ++mi)
        #pragma unroll
        for (int ni = 0; ni < 4; ++ni)
          acc[mi][ni] = __builtin_amdgcn_mfma_i32_16x16x64_i8(av[mi], bv[ni], acc[mi][ni], 0, 0, 0);
    }
    __syncthreads();
  }

  // ---- epilogue: C/D layout col = lane&15, row = (lane>>4)*4 + reg; scale by srow ----
  #pragma unroll
  for (int mi = 0; mi < 4; ++mi) {
    size_t r0 = brow + wr * 64 + mi * 16 + k8 * 4;
    float sc0 = srow[r0 + 0], sc1 = srow[r0 + 1], sc2 = srow[r0 + 2], sc3 = srow[r0 + 3];
    #pragma unroll
    for (int ni = 0; ni < 4; ++ni) {
      i32x4 v = acc[mi][ni];
      size_t c0 = bcol + wc * 64 + ni * 16 + fr;
      C[(r0 + 0) * N_DIM + c0] = sc0 * (float)v[0];
      C[(r0 + 1) * N_DIM + c0] = sc1 * (float)v[1];
      C[(r0 + 2) * N_DIM + c0] = sc2 * (float)v[2];
      C[(r0 + 3) * N_DIM + c0] = sc3 * (float)v[3];
    }
  }
}

// Fallback (only if ws_size is unexpectedly small): fused ternarize + fp32 tiled GEMM.
__global__ void tl_naive(const float* __restrict__ x, const float* __restrict__ W,
                         float* __restrict__ out) {
  __shared__ float sx[16][17];
  __shared__ float sw[16][17];
  int tx = threadIdx.x, ty = threadIdx.y;
  int row = blockIdx.y * 16 + ty;
  int col = blockIdx.x * 16 + tx;
  float acc = 0.f;
  for (int kt = 0; kt < K_DIM; kt += 16) {
    sx[ty][tx] = x[(size_t)row * K_DIM + kt + tx];
    float wv = W[(size_t)(blockIdx.x * 16 + ty) * K_DIM + kt + tx];
    sw[ty][tx] = (fabsf(wv) > 0.4f) ? ((wv > 0.f) ? 1.f : -1.f) : 0.f;
    __syncthreads();
    #pragma unroll
    for (int k = 0; k < 16; ++k) acc += sx[ty][k] * sw[tx][k];
    __syncthreads();
  }
  out[(size_t)row * N_DIM + col] = acc;
}

extern "C" void kernel_launch(void* const* d_in, const int* in_sizes, int n_in,
                              void* d_out, int out_size, void* d_ws, size_t ws_size,
                              hipStream_t stream) {
  const float* x = (const float*)d_in[0];
  const float* W = (const float*)d_in[1];
  float* out = (float*)d_out;

  const size_t xq_bytes = (size_t)M_DIM * K_DIM;          // 16 MiB
  const size_t wq_bytes = (size_t)N_DIM * K_DIM;          // 16 MiB
  const size_t need = xq_bytes + wq_bytes + M_DIM * sizeof(float);

  if (ws_size >= need) {
    signed char* xq = (signed char*)d_ws;                 // row-major i8 x
    signed char* wq = xq + xq_bytes;                      // row-major ternary W
    float* srow = (float*)(wq + wq_bytes);
    const int n8 = (int)(wq_bytes / 8);
    tl_quant_w<<<n8 / 256, 256, 0, stream>>>(W, wq, n8);
    tl_quant_x<<<M_DIM, 256, 0, stream>>>(x, xq, srow);
    tl_gemm<<<4096, 256, 0, stream>>>(xq, wq, srow, out);
  } else {
    dim3 g(N_DIM / 16, M_DIM / 16), b(16, 16);
    tl_naive<<<g, b, 0, stream>>>(x, W, out);
  }
}